// Round 3
// baseline (517.382 us; speedup 1.0000x reference)
//
#include <hip/hip_runtime.h>
#include <hip/hip_bf16.h>

#define T_SEQ 2048
#define L2E  1.44269504088896340736f
#define L2E2 2.88539008177792681472f

// ---------------- cross-lane / math helpers ----------------
template<int CTRL>
__device__ __forceinline__ float dppmov(float v) {
    // old=0, row_mask=0xF, bank_mask=0xF, bound_ctrl=true (invalid lanes -> 0)
    return __int_as_float(__builtin_amdgcn_update_dpp(
        0, __float_as_int(v), CTRL, 0xF, 0xF, true));
}
template<int CTRL>
__device__ __forceinline__ float dppadd(float v) { return v + dppmov<CTRL>(v); }
__device__ __forceinline__ float swzadd16(float v) {   // lane ^= 16 (within 32)
    return v + __int_as_float(__builtin_amdgcn_ds_swizzle(__float_as_int(v), 0x401F));
}
__device__ __forceinline__ float frcp(float x) { return __builtin_amdgcn_rcpf(x); }
__device__ __forceinline__ float ex2(float x)  { return __builtin_amdgcn_exp2f(x); }
// arg pre-scaled by log2(e):
__device__ __forceinline__ float sigm2(float x) { return frcp(1.0f + ex2(-x)); }
// arg pre-scaled by 2*log2(e):
__device__ __forceinline__ float tanh2(float x) { return fmaf(-2.0f, frcp(1.0f + ex2(x)), 1.0f); }

// ---------------------------------------------------------------------------
// Kernel 1: gx0[row][g] = (dot(x[row], w[g]) + b[g]) * scale[g]
// scale = log2e for r,z rows (g<6), 2*log2e for n rows (g>=6): lets the scan
// kernel use v_exp_f32 (exp2) directly with no argument scaling.
// One row per 64-lane wave-iteration; w slice in registers; DPP reduction.
// ---------------------------------------------------------------------------
__global__ __launch_bounds__(256) void gx0_kernel(
    const float* __restrict__ x,      // [131072,512]
    const float* __restrict__ w,      // [9,512]
    const float* __restrict__ bias,   // [9]
    float* __restrict__ gx0)          // [131072,9]
{
    const int lane = threadIdx.x & 63;
    const int gw   = (blockIdx.x * 256 + threadIdx.x) >> 6;   // 0..8191

    float4 wA[9], wB[9];
#pragma unroll
    for (int g = 0; g < 9; ++g) {
        const float s = (g < 6) ? L2E : L2E2;
        float4 a = *(const float4*)&w[g * 512 + lane * 4];
        float4 b = *(const float4*)&w[g * 512 + 256 + lane * 4];
        wA[g] = make_float4(a.x * s, a.y * s, a.z * s, a.w * s);
        wB[g] = make_float4(b.x * s, b.y * s, b.z * s, b.w * s);
    }
    const float bval = (lane < 9) ? bias[lane] * ((lane < 6) ? L2E : L2E2) : 0.f;

    size_t row0 = (size_t)gw * 16;
    const float4* xp = (const float4*)(x + row0 * 512);

    float4 xa = xp[lane];
    float4 xb = xp[64 + lane];

#pragma unroll 1
    for (int i = 0; i < 16; ++i) {
        float4 na = xa, nb = xb;
        if (i < 15) {
            na = xp[(i + 1) * 128 + lane];
            nb = xp[(i + 1) * 128 + 64 + lane];
        }
        float r[9];
#pragma unroll
        for (int g = 0; g < 9; ++g) {
            float s = xa.x * wA[g].x;
            s = fmaf(xa.y, wA[g].y, s);
            s = fmaf(xa.z, wA[g].z, s);
            s = fmaf(xa.w, wA[g].w, s);
            s = fmaf(xb.x, wB[g].x, s);
            s = fmaf(xb.y, wB[g].y, s);
            s = fmaf(xb.z, wB[g].z, s);
            s = fmaf(xb.w, wB[g].w, s);
            s = dppadd<0xB1>(s);            // quad_perm [1,0,3,2]
            s = dppadd<0x4E>(s);            // quad_perm [2,3,0,1]
            s = dppadd<0x124>(s);           // row_ror:4
            s = dppadd<0x128>(s);           // row_ror:8
            s = swzadd16(s);
            s += __shfl_xor(s, 32, 64);
            r[g] = s;
        }
        float o = r[0];
#pragma unroll
        for (int g = 1; g < 9; ++g) o = (lane == g) ? r[g] : o;
        if (lane < 9) gx0[(row0 + i) * 9 + lane] = o + bval;
        xa = na; xb = nb;
    }
}

// ---------------------------------------------------------------------------
// Kernel 2: pipelined 4-layer GRU scan, TWO register-interleaved batch
// streams per wave (cross-stream ILP fills dependency-latency stalls).
// 8 blocks x 64 threads; lane = grp*16 + l*4 + j; stream A batch = blk*8+grp,
// stream B batch = blk*8+grp+4. DPP-only cross-lane comm.
// ---------------------------------------------------------------------------
struct Stream {
    float h;
    float gp[8][3];   // depth-8 rotating gx prefetch
    int   voff;       // element offset of next prefetch (t = s+8)
    int   soff;       // element offset of this step's out store (t = s-3)
};

template<int MODE>  // 0=prologue (act: t>=0), 1=main (no checks), 2=epilogue (act: t<T, no loads)
__device__ __forceinline__ void gstep(
    Stream& S, const int slot, const int s,
    const float (&wi)[3][3], const float (&wh)[3][3], const float (&bh)[3],
    const float bi2, const int l, const bool is0, const bool do_store,
    const float* __restrict__ gx0, float* __restrict__ out)
{
    float hv0 = dppmov<0x00>(S.h);     // broadcast quad lane0 (j=0)
    float hv1 = dppmov<0x55>(S.h);     // j=1
    float hv2 = dppmov<0xAA>(S.h);     // j=2
    float xv0 = dppmov<0x114>(hv0);    // row_shr:4 -> prev layer (0 for l==0)
    float xv1 = dppmov<0x114>(hv1);
    float xv2 = dppmov<0x114>(hv2);
    float c0 = is0 ? S.gp[slot][0] : 0.f;    // b_ih folded into bh for r,z (l>0)
    float c1 = is0 ? S.gp[slot][1] : 0.f;
    float c2 = is0 ? S.gp[slot][2] : bi2;    // n-gate input bias must stay on x side
    if (MODE != 2) {
        S.gp[slot][0] = gx0[S.voff];
        S.gp[slot][1] = gx0[S.voff + 3];
        S.gp[slot][2] = gx0[S.voff + 6];
        S.voff += 576;
    }
    float gxr = fmaf(wi[0][0], xv0, fmaf(wi[0][1], xv1, fmaf(wi[0][2], xv2, c0)));
    float gxz = fmaf(wi[1][0], xv0, fmaf(wi[1][1], xv1, fmaf(wi[1][2], xv2, c1)));
    float gxn = fmaf(wi[2][0], xv0, fmaf(wi[2][1], xv1, fmaf(wi[2][2], xv2, c2)));
    float ghr = fmaf(wh[0][0], hv0, fmaf(wh[0][1], hv1, fmaf(wh[0][2], hv2, bh[0])));
    float ghz = fmaf(wh[1][0], hv0, fmaf(wh[1][1], hv1, fmaf(wh[1][2], hv2, bh[1])));
    float ghn = fmaf(wh[2][0], hv0, fmaf(wh[2][1], hv1, fmaf(wh[2][2], hv2, bh[2])));
    float rr = sigm2(gxr + ghr);
    float zz = sigm2(gxz + ghz);
    float nn = tanh2(fmaf(rr, ghn, gxn));
    float hn = fmaf(zz, S.h - nn, nn);
    if (MODE == 1) {
        S.h = hn;
        if (do_store) out[S.soff] = hn;
    } else {
        const int t = s - l;
        const bool act = (MODE == 0) ? (t >= 0) : (t < T_SEQ);
        S.h = act ? hn : S.h;
        if (do_store && act) out[S.soff] = hn;
    }
    S.soff += 192;
}

__global__ __launch_bounds__(64) void gru_scan(
    const float* __restrict__ gx0,        // [T*64*9] pre-scaled, incl. b_ih0
    const float* __restrict__ hxs,        // [4*64*3]
    const float* __restrict__ w_hh0,      // [9*3]
    const float* __restrict__ b_hh0,      // [9]
    const float* __restrict__ w_ih_rest,  // [3*9*3]
    const float* __restrict__ w_hh_rest,  // [3*9*3]
    const float* __restrict__ b_ih_rest,  // [3*9]
    const float* __restrict__ b_hh_rest,  // [3*9]
    float* __restrict__ out)              // [T*64*3 + 4*64*3]
{
    const int lane = threadIdx.x;
    const int grp  = lane >> 4;
    const int r    = lane & 15;
    const int l    = r >> 2;
    const int j    = r & 3;
    const bool jok = (j < 3);
    const bool is0 = (l == 0);
    const bool do_store = (l == 3) && jok;
    const int  bA  = blockIdx.x * 8 + grp;
    const int  bB  = bA + 4;
    const int  row0 = jok ? j : 0;

    // per-lane weights, pre-scaled (r,z: log2e; n: 2*log2e); b_ih folded into
    // bh for r,z; n-gate keeps separate input bias bi2 (r multiplies only nh).
    float wi[3][3], wh[3][3], bh[3];
    const float sc[3] = {L2E, L2E, L2E2};
#pragma unroll
    for (int m = 0; m < 3; ++m) {
        const int row = m * 3 + row0;
        if (l == 0) {
            bh[m] = b_hh0[row] * sc[m];
#pragma unroll
            for (int k = 0; k < 3; ++k) { wi[m][k] = 0.f; wh[m][k] = w_hh0[row * 3 + k] * sc[m]; }
        } else {
            float bb = b_hh_rest[(l - 1) * 9 + row];
            if (m < 2) bb += b_ih_rest[(l - 1) * 9 + row];
            bh[m] = bb * sc[m];
#pragma unroll
            for (int k = 0; k < 3; ++k) {
                wi[m][k] = w_ih_rest[((l - 1) * 9 + row) * 3 + k] * sc[m];
                wh[m][k] = w_hh_rest[((l - 1) * 9 + row) * 3 + k] * sc[m];
            }
        }
    }
    const float bi2 = is0 ? 0.f : b_ih_rest[(l - 1) * 9 + 6 + row0] * L2E2;

    Stream A, B;
    A.h = jok ? hxs[(l * 64 + bA) * 3 + j] : 0.f;
    B.h = jok ? hxs[(l * 64 + bB) * 3 + j] : 0.f;
    const int baseA = bA * 9 + row0;
    const int baseB = bB * 9 + row0;
#pragma unroll
    for (int p = 0; p < 8; ++p) {
        A.gp[p][0] = gx0[baseA + p * 576];
        A.gp[p][1] = gx0[baseA + p * 576 + 3];
        A.gp[p][2] = gx0[baseA + p * 576 + 6];
        B.gp[p][0] = gx0[baseB + p * 576];
        B.gp[p][1] = gx0[baseB + p * 576 + 3];
        B.gp[p][2] = gx0[baseB + p * 576 + 6];
    }
    A.voff = baseA + 8 * 576;
    B.voff = baseB + 8 * 576;
    A.soff = -3 * 192 + bA * 3 + j;
    B.soff = -3 * 192 + bB * 3 + j;

    // prologue: s = 0..7 (t>=0 checks; prefetch t=8..15, no clamp needed)
#pragma unroll
    for (int p = 0; p < 8; ++p) {
        gstep<0>(A, p, p, wi, wh, bh, bi2, l, is0, do_store, gx0, out);
        gstep<0>(B, p, p, wi, wh, bh, bi2, l, is0, do_store, gx0, out);
    }
    // main: s = 8..2039, no checks, prefetch t = s+8 <= 2047
#pragma unroll 1
    for (int s0 = 8; s0 < 2040; s0 += 8) {
#pragma unroll
        for (int p = 0; p < 8; ++p) {
            gstep<1>(A, p, 0, wi, wh, bh, bi2, l, is0, do_store, gx0, out);
            gstep<1>(B, p, 0, wi, wh, bh, bi2, l, is0, do_store, gx0, out);
        }
    }
    // epilogue: s = 2040..2055 (t<T checks, no loads)
#pragma unroll 1
    for (int s0 = 2040; s0 < 2056; s0 += 8) {
#pragma unroll
        for (int p = 0; p < 8; ++p) {
            gstep<2>(A, p, s0 + p, wi, wh, bh, bi2, l, is0, do_store, gx0, out);
            gstep<2>(B, p, s0 + p, wi, wh, bh, bi2, l, is0, do_store, gx0, out);
        }
    }
    if (jok) {
        out[T_SEQ * 192 + (l * 64 + bA) * 3 + j] = A.h;
        out[T_SEQ * 192 + (l * 64 + bB) * 3 + j] = B.h;
    }
}

// ---------------------------------------------------------------------------
extern "C" void kernel_launch(void* const* d_in, const int* in_sizes, int n_in,
                              void* d_out, int out_size, void* d_ws, size_t ws_size,
                              hipStream_t stream) {
    const float* x         = (const float*)d_in[0];
    const float* hxs       = (const float*)d_in[1];
    const float* w_ih0     = (const float*)d_in[2];
    const float* w_hh0     = (const float*)d_in[3];
    const float* b_ih0     = (const float*)d_in[4];
    const float* b_hh0     = (const float*)d_in[5];
    const float* w_ih_rest = (const float*)d_in[6];
    const float* w_hh_rest = (const float*)d_in[7];
    const float* b_ih_rest = (const float*)d_in[8];
    const float* b_hh_rest = (const float*)d_in[9];
    float* out = (float*)d_out;
    float* gx0 = (float*)d_ws;   // T*64*9*4 = 4.72 MB

    hipLaunchKernelGGL(gx0_kernel, dim3(2048), dim3(256), 0, stream,
                       x, w_ih0, b_ih0, gx0);
    hipLaunchKernelGGL(gru_scan, dim3(8), dim3(64), 0, stream,
                       gx0, hxs, w_hh0, b_hh0, w_ih_rest, w_hh_rest,
                       b_ih_rest, b_hh_rest, out);
}

// Round 4
// 273.885 us; speedup vs baseline: 1.8890x; 1.8890x over previous
//
#include <hip/hip_runtime.h>
#include <hip/hip_bf16.h>

#define T_SEQ 2048
#define NCHUNK 129            // 129 chunks x 16 wave-steps = 2064 steps
#define L2E  1.44269504088896340736f
#define L2E2 2.88539008177792681472f

// ---------------- cross-lane / math helpers ----------------
template<int CTRL>
__device__ __forceinline__ float dppmov(float v) {
    // old=0, row_mask=0xF, bank_mask=0xF, bound_ctrl=true (invalid lanes -> 0)
    return __int_as_float(__builtin_amdgcn_update_dpp(
        0, __float_as_int(v), CTRL, 0xF, 0xF, true));
}
template<int CTRL>
__device__ __forceinline__ float dppadd(float v) { return v + dppmov<CTRL>(v); }
__device__ __forceinline__ float swzadd16(float v) {   // lane ^= 16 (within 32)
    return v + __int_as_float(__builtin_amdgcn_ds_swizzle(__float_as_int(v), 0x401F));
}
__device__ __forceinline__ float frcp(float x) { return __builtin_amdgcn_rcpf(x); }
__device__ __forceinline__ float ex2(float x)  { return __builtin_amdgcn_exp2f(x); }
__device__ __forceinline__ float sigm2(float x) { return frcp(1.0f + ex2(-x)); }  // arg pre-scaled log2e
__device__ __forceinline__ float tanh2(float x) { return fmaf(-2.0f, frcp(1.0f + ex2(x)), 1.0f); } // arg pre-scaled 2*log2e

#define RING_BARRIER() asm volatile("s_waitcnt lgkmcnt(0)\ns_barrier" ::: "memory")

// ---------------------------------------------------------------------------
// Kernel 1: gx0[row][g] = (dot(x[row], w[g]) + b[g]) * scale[g]
// scale = log2e (g<6) / 2*log2e (g>=6) so the scan uses exp2 directly.
// ---------------------------------------------------------------------------
__global__ __launch_bounds__(256) void gx0_kernel(
    const float* __restrict__ x,      // [131072,512]
    const float* __restrict__ w,      // [9,512]
    const float* __restrict__ bias,   // [9]
    float* __restrict__ gx0)          // [131072,9]
{
    const int lane = threadIdx.x & 63;
    const int gw   = (blockIdx.x * 256 + threadIdx.x) >> 6;

    float4 wA[9], wB[9];
#pragma unroll
    for (int g = 0; g < 9; ++g) {
        const float s = (g < 6) ? L2E : L2E2;
        float4 a = *(const float4*)&w[g * 512 + lane * 4];
        float4 b = *(const float4*)&w[g * 512 + 256 + lane * 4];
        wA[g] = make_float4(a.x * s, a.y * s, a.z * s, a.w * s);
        wB[g] = make_float4(b.x * s, b.y * s, b.z * s, b.w * s);
    }
    const float bval = (lane < 9) ? bias[lane] * ((lane < 6) ? L2E : L2E2) : 0.f;

    size_t row0 = (size_t)gw * 16;
    const float4* xp = (const float4*)(x + row0 * 512);

    float4 xa = xp[lane];
    float4 xb = xp[64 + lane];

#pragma unroll 1
    for (int i = 0; i < 16; ++i) {
        float4 na = xa, nb = xb;
        if (i < 15) {
            na = xp[(i + 1) * 128 + lane];
            nb = xp[(i + 1) * 128 + 64 + lane];
        }
        float r[9];
#pragma unroll
        for (int g = 0; g < 9; ++g) {
            float s = xa.x * wA[g].x;
            s = fmaf(xa.y, wA[g].y, s);
            s = fmaf(xa.z, wA[g].z, s);
            s = fmaf(xa.w, wA[g].w, s);
            s = fmaf(xb.x, wB[g].x, s);
            s = fmaf(xb.y, wB[g].y, s);
            s = fmaf(xb.z, wB[g].z, s);
            s = fmaf(xb.w, wB[g].w, s);
            s = dppadd<0xB1>(s);            // quad_perm [1,0,3,2]
            s = dppadd<0x4E>(s);            // quad_perm [2,3,0,1]
            s = dppadd<0x124>(s);           // row_ror:4
            s = dppadd<0x128>(s);           // row_ror:8
            s = swzadd16(s);
            s += __shfl_xor(s, 32, 64);
            r[g] = s;
        }
        float o = r[0];
#pragma unroll
        for (int g = 1; g < 9; ++g) o = (lane == g) ? r[g] : o;
        if (lane < 9) gx0[(row0 + i) * 9 + lane] = o + bval;
        xa = na; xb = nb;
    }
}

// ---------------------------------------------------------------------------
// Kernel 2: producer-consumer GRU scan.
// 16 blocks x 128 threads (2 waves). Wave 0: pipelined 4-layer scan, output
// to LDS ring only (NO global stores in the recurrence -> vmcnt FIFO holds
// only prefetch loads). Wave 1: drains ring to global each 16-step chunk.
// Raw s_barrier with lgkmcnt-only wait keeps prefetch loads in flight.
// ---------------------------------------------------------------------------
struct PState {
    float h;
    float gp[8][3];   // depth-8 rotating gx prefetch (layer-0 lanes)
    int   voff;       // element offset of next prefetch
};

// MODE: 0=prologue (act: t>=0, load), 1=main (no checks, load), 2=tail (act: t<T, no load)
template<int MODE>
__device__ __forceinline__ void gstep(
    PState& S, const int slot, const int t,
    const float (&wi)[3][3], const float (&wh)[3][3], const float (&bh)[3],
    const float bi2, const bool is0, const bool do_store,
    const float* __restrict__ gx0, float* rw, const int ridx)
{
    float hv0 = dppmov<0x00>(S.h);     // broadcast quad j=0 (own layer)
    float hv1 = dppmov<0x55>(S.h);     // j=1
    float hv2 = dppmov<0xAA>(S.h);     // j=2
    float xv0 = dppmov<0x114>(hv0);    // row_shr:4 -> prev layer (0 for l==0)
    float xv1 = dppmov<0x114>(hv1);
    float xv2 = dppmov<0x114>(hv2);
    float c0 = is0 ? S.gp[slot][0] : 0.f;    // b_ih folded into bh for r,z (l>0)
    float c1 = is0 ? S.gp[slot][1] : 0.f;
    float c2 = is0 ? S.gp[slot][2] : bi2;    // n-gate input bias stays on x side
    if (MODE != 2) {
        S.gp[slot][0] = gx0[S.voff];
        S.gp[slot][1] = gx0[S.voff + 3];
        S.gp[slot][2] = gx0[S.voff + 6];
        S.voff += 576;
    }
    float gxr = fmaf(wi[0][0], xv0, fmaf(wi[0][1], xv1, fmaf(wi[0][2], xv2, c0)));
    float gxz = fmaf(wi[1][0], xv0, fmaf(wi[1][1], xv1, fmaf(wi[1][2], xv2, c1)));
    float gxn = fmaf(wi[2][0], xv0, fmaf(wi[2][1], xv1, fmaf(wi[2][2], xv2, c2)));
    float ghr = fmaf(wh[0][0], hv0, fmaf(wh[0][1], hv1, fmaf(wh[0][2], hv2, bh[0])));
    float ghz = fmaf(wh[1][0], hv0, fmaf(wh[1][1], hv1, fmaf(wh[1][2], hv2, bh[1])));
    float ghn = fmaf(wh[2][0], hv0, fmaf(wh[2][1], hv1, fmaf(wh[2][2], hv2, bh[2])));
    float rr = sigm2(gxr + ghr);
    float zz = sigm2(gxz + ghz);
    float nn = tanh2(fmaf(rr, ghn, gxn));
    float hn = fmaf(zz, S.h - nn, nn);
    if (MODE == 0) {
        S.h = (t >= 0) ? hn : S.h;
    } else if (MODE == 2) {
        S.h = (t < T_SEQ) ? hn : S.h;
    } else {
        S.h = hn;
    }
    if (do_store) rw[ridx] = hn;   // LDS ring; consumer guards t-range
}

__global__ __launch_bounds__(128) void gru_scan(
    const float* __restrict__ gx0,        // [T*64*9] pre-scaled, incl. b_ih0
    const float* __restrict__ hxs,        // [4*64*3]
    const float* __restrict__ w_hh0,      // [9*3]
    const float* __restrict__ b_hh0,      // [9]
    const float* __restrict__ w_ih_rest,  // [3*9*3]
    const float* __restrict__ w_hh_rest,  // [3*9*3]
    const float* __restrict__ b_ih_rest,  // [3*9]
    const float* __restrict__ b_hh_rest,  // [3*9]
    float* __restrict__ out)              // [T*64*3 + 4*64*3]
{
    __shared__ float ring[2 * 192];       // 2 chunks x 16 steps x 12 values
    const int tid  = threadIdx.x;
    const int lane = tid & 63;

    if (tid < 64) {
        // ------------------------- producer wave -------------------------
        const int grp = lane >> 4;
        const int r   = lane & 15;
        const int l   = r >> 2;
        const int j   = r & 3;
        const bool jok = (j < 3);
        const bool is0 = (l == 0);
        const bool do_store = (l == 3) && jok;
        const int  b   = blockIdx.x * 4 + grp;
        const int  row0 = jok ? j : 0;

        float wi[3][3], wh[3][3], bh[3];
        const float sc[3] = {L2E, L2E, L2E2};
#pragma unroll
        for (int m = 0; m < 3; ++m) {
            const int row = m * 3 + row0;
            if (l == 0) {
                bh[m] = b_hh0[row] * sc[m];
#pragma unroll
                for (int k = 0; k < 3; ++k) { wi[m][k] = 0.f; wh[m][k] = w_hh0[row * 3 + k] * sc[m]; }
            } else {
                float bb = b_hh_rest[(l - 1) * 9 + row];
                if (m < 2) bb += b_ih_rest[(l - 1) * 9 + row];
                bh[m] = bb * sc[m];
#pragma unroll
                for (int k = 0; k < 3; ++k) {
                    wi[m][k] = w_ih_rest[((l - 1) * 9 + row) * 3 + k] * sc[m];
                    wh[m][k] = w_hh_rest[((l - 1) * 9 + row) * 3 + k] * sc[m];
                }
            }
        }
        const float bi2 = is0 ? 0.f : b_ih_rest[(l - 1) * 9 + 6 + row0] * L2E2;

        PState S;
        S.h = jok ? hxs[(l * 64 + b) * 3 + j] : 0.f;
        const int base = b * 9 + row0;
#pragma unroll
        for (int p = 0; p < 8; ++p) {
            S.gp[p][0] = gx0[base + p * 576];
            S.gp[p][1] = gx0[base + p * 576 + 3];
            S.gp[p][2] = gx0[base + p * 576 + 6];
        }
        S.voff = base + 8 * 576;

        const int rlane = grp * 3 + j;    // ring column for do_store lanes

        // chunk 0: s = 0..15, t>=0 checks, prefetch t=8..23
        {
            float* rw = &ring[0 + rlane];
#pragma unroll
            for (int p = 0; p < 16; ++p)
                gstep<0>(S, p & 7, p - l, wi, wh, bh, bi2, is0, do_store, gx0, rw, p * 12);
            RING_BARRIER();
        }
        // chunks 1..126: s = 16..2031, no checks, prefetch t <= 2039
#pragma unroll 1
        for (int c = 1; c < 127; ++c) {
            float* rw = &ring[(c & 1) * 192 + rlane];
#pragma unroll
            for (int p = 0; p < 16; ++p)
                gstep<1>(S, p & 7, 0, wi, wh, bh, bi2, is0, do_store, gx0, rw, p * 12);
            RING_BARRIER();
        }
        // chunk 127: s = 2032..2047; first 8 prefetch t=2040..2047, last 8 no load
        {
            float* rw = &ring[(127 & 1) * 192 + rlane];
#pragma unroll
            for (int p = 0; p < 8; ++p)
                gstep<1>(S, p, 0, wi, wh, bh, bi2, is0, do_store, gx0, rw, p * 12);
#pragma unroll
            for (int p = 8; p < 16; ++p)
                gstep<2>(S, p & 7, 2032 + p - l, wi, wh, bh, bi2, is0, do_store, gx0, rw, p * 12);
            RING_BARRIER();
        }
        // chunk 128: s = 2048..2063, t<T checks, no loads
        {
            float* rw = &ring[(128 & 1) * 192 + rlane];
#pragma unroll
            for (int p = 0; p < 16; ++p)
                gstep<2>(S, p & 7, 2048 + p - l, wi, wh, bh, bi2, is0, do_store, gx0, rw, p * 12);
            RING_BARRIER();
        }
        // final hidden states (once, off the critical loop)
        if (jok) out[T_SEQ * 192 + (l * 64 + b) * 3 + j] = S.h;
    } else {
        // ------------------------- consumer wave -------------------------
        const int obase = (int)blockIdx.x * 12;
        int tt[3], ooff[3], v_[3];
#pragma unroll
        for (int it = 0; it < 3; ++it) {
            int v  = it * 64 + lane;          // 0..191
            int st = v / 12;                  // step within chunk
            int pos = v - st * 12;
            v_[it]   = v;
            tt[it]   = st - 3;                // t for chunk 0 (l==3 lags by 3)
            ooff[it] = (st - 3) * 192 + obase + pos;
        }
#pragma unroll 1
        for (int c = 0; c < NCHUNK; ++c) {
            RING_BARRIER();
            const float* rb = &ring[(c & 1) * 192];
#pragma unroll
            for (int it = 0; it < 3; ++it) {
                float val = rb[v_[it]];
                if (tt[it] >= 0 && tt[it] < T_SEQ) out[ooff[it]] = val;
                tt[it]   += 16;
                ooff[it] += 16 * 192;
            }
        }
    }
}

// ---------------------------------------------------------------------------
extern "C" void kernel_launch(void* const* d_in, const int* in_sizes, int n_in,
                              void* d_out, int out_size, void* d_ws, size_t ws_size,
                              hipStream_t stream) {
    const float* x         = (const float*)d_in[0];
    const float* hxs       = (const float*)d_in[1];
    const float* w_ih0     = (const float*)d_in[2];
    const float* w_hh0     = (const float*)d_in[3];
    const float* b_ih0     = (const float*)d_in[4];
    const float* b_hh0     = (const float*)d_in[5];
    const float* w_ih_rest = (const float*)d_in[6];
    const float* w_hh_rest = (const float*)d_in[7];
    const float* b_ih_rest = (const float*)d_in[8];
    const float* b_hh_rest = (const float*)d_in[9];
    float* out = (float*)d_out;
    float* gx0 = (float*)d_ws;   // T*64*9*4 = 4.72 MB

    hipLaunchKernelGGL(gx0_kernel, dim3(2048), dim3(256), 0, stream,
                       x, w_ih0, b_ih0, gx0);
    hipLaunchKernelGGL(gru_scan, dim3(16), dim3(128), 0, stream,
                       gx0, hxs, w_hh0, b_hh0, w_ih_rest, w_hh_rest,
                       b_ih_rest, b_hh_rest, out);
}

// Round 5
// 232.109 us; speedup vs baseline: 2.2290x; 1.1800x over previous
//
#include <hip/hip_runtime.h>
#include <hip/hip_bf16.h>

#define T_SEQ 2048
#define CHUNK 16
#define NCHUNK 129           // 129 chunks x 16 steps = 2064 wave-steps >= 2051
#define L2E  1.44269504088896340736f
#define L2E2 2.88539008177792681472f

// ---------------- cross-lane / math helpers ----------------
template<int CTRL>
__device__ __forceinline__ float dppmov(float v) {
    return __int_as_float(__builtin_amdgcn_update_dpp(
        0, __float_as_int(v), CTRL, 0xF, 0xF, true));
}
template<int CTRL>
__device__ __forceinline__ float dppadd(float v) { return v + dppmov<CTRL>(v); }
__device__ __forceinline__ float swzadd16(float v) {
    return v + __int_as_float(__builtin_amdgcn_ds_swizzle(__float_as_int(v), 0x401F));
}
__device__ __forceinline__ float frcp(float x) { return __builtin_amdgcn_rcpf(x); }
__device__ __forceinline__ float ex2(float x)  { return __builtin_amdgcn_exp2f(x); }
__device__ __forceinline__ float sigm2(float x) { return frcp(1.0f + ex2(-x)); }  // arg pre-scaled log2e
__device__ __forceinline__ float tanh2(float x) { return fmaf(-2.0f, frcp(1.0f + ex2(x)), 1.0f); } // pre-scaled 2*log2e

#define RING_BARRIER() asm volatile("s_waitcnt lgkmcnt(0)\ns_barrier" ::: "memory")

// ---------------------------------------------------------------------------
// Kernel 1 (unchanged, at HBM roofline): gx0[row][g] = (dot+b)*scale
// ---------------------------------------------------------------------------
__global__ __launch_bounds__(256) void gx0_kernel(
    const float* __restrict__ x, const float* __restrict__ w,
    const float* __restrict__ bias, float* __restrict__ gx0)
{
    const int lane = threadIdx.x & 63;
    const int gw   = (blockIdx.x * 256 + threadIdx.x) >> 6;

    float4 wA[9], wB[9];
#pragma unroll
    for (int g = 0; g < 9; ++g) {
        const float s = (g < 6) ? L2E : L2E2;
        float4 a = *(const float4*)&w[g * 512 + lane * 4];
        float4 b = *(const float4*)&w[g * 512 + 256 + lane * 4];
        wA[g] = make_float4(a.x * s, a.y * s, a.z * s, a.w * s);
        wB[g] = make_float4(b.x * s, b.y * s, b.z * s, b.w * s);
    }
    const float bval = (lane < 9) ? bias[lane] * ((lane < 6) ? L2E : L2E2) : 0.f;

    size_t row0 = (size_t)gw * 16;
    const float4* xp = (const float4*)(x + row0 * 512);
    float4 xa = xp[lane];
    float4 xb = xp[64 + lane];

#pragma unroll 1
    for (int i = 0; i < 16; ++i) {
        float4 na = xa, nb = xb;
        if (i < 15) {
            na = xp[(i + 1) * 128 + lane];
            nb = xp[(i + 1) * 128 + 64 + lane];
        }
        float r[9];
#pragma unroll
        for (int g = 0; g < 9; ++g) {
            float s = xa.x * wA[g].x;
            s = fmaf(xa.y, wA[g].y, s);
            s = fmaf(xa.z, wA[g].z, s);
            s = fmaf(xa.w, wA[g].w, s);
            s = fmaf(xb.x, wB[g].x, s);
            s = fmaf(xb.y, wB[g].y, s);
            s = fmaf(xb.z, wB[g].z, s);
            s = fmaf(xb.w, wB[g].w, s);
            s = dppadd<0xB1>(s);
            s = dppadd<0x4E>(s);
            s = dppadd<0x124>(s);
            s = dppadd<0x128>(s);
            s = swzadd16(s);
            s += __shfl_xor(s, 32, 64);
            r[g] = s;
        }
        float o = r[0];
#pragma unroll
        for (int g = 1; g < 9; ++g) o = (lane == g) ? r[g] : o;
        if (lane < 9) gx0[(row0 + i) * 9 + lane] = o + bval;
        xa = na; xb = nb;
    }
}

// ---------------------------------------------------------------------------
// Kernel 2: producer/consumer GRU scan, zero global ops in producer loop.
// LDS: gxb[3 bufs][16 steps][64 lanes] float4 (l0 lanes: gx values staged by
// consumer; l>0 lanes: constants (0,0,bi2) written once) + hn ring [2][16][64].
// Producer step: 1 ds_read_b128 + 6 DPP + 18 FMA + 2 add + 2 sigm + tanh +
// 1 ds_write. No vmcnt, no exec churn, no cndmask.
// ---------------------------------------------------------------------------
__global__ __launch_bounds__(128) void gru_scan(
    const float* __restrict__ gx0,        // [T*64*9] pre-scaled, incl. b_ih0
    const float* __restrict__ hxs,
    const float* __restrict__ w_hh0, const float* __restrict__ b_hh0,
    const float* __restrict__ w_ih_rest, const float* __restrict__ w_hh_rest,
    const float* __restrict__ b_ih_rest, const float* __restrict__ b_hh_rest,
    float* __restrict__ out)              // [T*64*3 + 4*64*3]
{
    __shared__ float4 gxb[3][CHUNK][64];   // 48 KB
    __shared__ float  ring[2][CHUNK][64];  // 8 KB
    const int tid  = threadIdx.x;
    const int lane = tid & 63;

    if (tid < 64) {
        // ============================ producer ============================
        const int grp = lane >> 4;
        const int r   = lane & 15;
        const int l   = r >> 2;
        const int j   = r & 3;
        const bool jok = (j < 3);
        const bool is0 = (l == 0);
        const int  b   = blockIdx.x * 4 + grp;
        const int  row0 = jok ? j : 0;

        float wi[3][3], wh[3][3], bh[3];
        const float sc[3] = {L2E, L2E, L2E2};
#pragma unroll
        for (int m = 0; m < 3; ++m) {
            const int row = m * 3 + row0;
            if (l == 0) {
                bh[m] = b_hh0[row] * sc[m];
#pragma unroll
                for (int k = 0; k < 3; ++k) { wi[m][k] = 0.f; wh[m][k] = w_hh0[row * 3 + k] * sc[m]; }
            } else {
                float bb = b_hh_rest[(l - 1) * 9 + row];
                if (m < 2) bb += b_ih_rest[(l - 1) * 9 + row];
                bh[m] = bb * sc[m];
#pragma unroll
                for (int k = 0; k < 3; ++k) {
                    wi[m][k] = w_ih_rest[((l - 1) * 9 + row) * 3 + k] * sc[m];
                    wh[m][k] = w_hh_rest[((l - 1) * 9 + row) * 3 + k] * sc[m];
                }
            }
        }
        const float bi2 = is0 ? 0.f : b_ih_rest[(l - 1) * 9 + 6 + row0] * L2E2;

        // constant gx slots for lanes the consumer never writes (l>0, or j==3)
        if (!(is0 && jok)) {
            const float4 cv = make_float4(0.f, 0.f, bi2, 0.f);
#pragma unroll
            for (int f = 0; f < 3; ++f)
                for (int st = 0; st < CHUNK; ++st)
                    gxb[f][st][lane] = cv;
        }
        float h = jok ? hxs[(l * 64 + b) * 3 + j] : 0.f;

        RING_BARRIER();   // consumer has prefilled bufs 0,1

        float4 gp[4];
#pragma unroll
        for (int k = 0; k < 4; ++k) gp[k] = gxb[0][k][lane];

        int bufc = 0;

#define GSTEP(P, MODE, CC0, TT)                                                     \
        do {                                                                        \
            float4 cc = gp[(P) & 3];                                                \
            if ((P) < CHUNK - 4) gp[(P) & 3] = gxb[bufc][(P) + 4][lane];            \
            else                 gp[(P) & 3] = gxb[bufn][(P) - (CHUNK - 4)][lane];  \
            float hv0 = dppmov<0x00>(h);                                            \
            float hv1 = dppmov<0x55>(h);                                            \
            float hv2 = dppmov<0xAA>(h);                                            \
            float xv0 = dppmov<0x114>(hv0);                                         \
            float xv1 = dppmov<0x114>(hv1);                                         \
            float xv2 = dppmov<0x114>(hv2);                                         \
            float gxr = fmaf(wi[0][0], xv0, fmaf(wi[0][1], xv1, fmaf(wi[0][2], xv2, cc.x))); \
            float gxz = fmaf(wi[1][0], xv0, fmaf(wi[1][1], xv1, fmaf(wi[1][2], xv2, cc.y))); \
            float gxn = fmaf(wi[2][0], xv0, fmaf(wi[2][1], xv1, fmaf(wi[2][2], xv2, cc.z))); \
            float ghr = fmaf(wh[0][0], hv0, fmaf(wh[0][1], hv1, fmaf(wh[0][2], hv2, bh[0]))); \
            float ghz = fmaf(wh[1][0], hv0, fmaf(wh[1][1], hv1, fmaf(wh[1][2], hv2, bh[1]))); \
            float ghn = fmaf(wh[2][0], hv0, fmaf(wh[2][1], hv1, fmaf(wh[2][2], hv2, bh[2]))); \
            float rr = sigm2(gxr + ghr);                                            \
            float zz = sigm2(gxz + ghz);                                            \
            float nn = tanh2(fmaf(rr, ghn, gxn));                                   \
            float hn = fmaf(zz, h - nn, nn);                                        \
            if (MODE == 0)      h = ((TT) >= 0)    ? hn : h;                        \
            else if (MODE == 2) h = ((TT) < T_SEQ) ? hn : h;                        \
            else                h = hn;                                             \
            ring[CB][(P)][lane] = hn;                                               \
        } while (0)

        // ---- chunk 0: steps 0..15, t>=0 guard on first 4 ----
        {
            const int bufn = 1; const int CB = 0;
#pragma unroll
            for (int p = 0; p < 4; ++p)  GSTEP(p, 0, 0, p - l);
#pragma unroll
            for (int p = 4; p < 16; ++p) GSTEP(p, 1, 0, 0);
            RING_BARRIER();
            bufc = 1;
        }
        // ---- chunks 1..127: no guards ----
#pragma unroll 1
        for (int c = 1; c < 128; ++c) {
            const int bufn = (bufc == 2) ? 0 : bufc + 1;
            const int CB = c & 1;
#pragma unroll
            for (int p = 0; p < 16; ++p) GSTEP(p, 1, 0, 0);
            RING_BARRIER();
            bufc = bufn;
        }
        // ---- chunk 128 tail: s = 2048..2051, t<T guard ----
        {
            const int bufn = (bufc == 2) ? 0 : bufc + 1;
            const int CB = 0;   // 128 & 1 == 0
#pragma unroll
            for (int p = 0; p < 4; ++p) GSTEP(p, 2, 0, 2048 + p - l);
            RING_BARRIER();
        }
#undef GSTEP
        // final hidden states (once, off critical path)
        if (jok) out[(size_t)T_SEQ * 192 + (l * 64 + b) * 3 + j] = h;
    } else {
        // ============================ consumer ============================
        const int blk = blockIdx.x;
        float* gxs = (float*)gxb;

        // fill buffer f with gx for t0..t0+15 (l0 lane slots only)
#define FILL(F, T0)                                                                 \
        do {                                                                        \
            _Pragma("unroll")                                                       \
            for (int k = 0; k < 9; ++k) {                                           \
                int i  = k * 64 + lane;                                             \
                int st = i / 36;                                                    \
                int pos = i - st * 36;                                              \
                int bl = pos / 9;                                                   \
                int g  = pos - bl * 9;                                              \
                int m  = g / 3;                                                     \
                int jj = g - m * 3;                                                 \
                float val = gx0[(size_t)((T0) + st) * 576 + (blk * 4 + bl) * 9 + g];\
                gxs[(((F) * CHUNK + st) * 64 + bl * 16 + jj) * 4 + m] = val;        \
            }                                                                       \
        } while (0)

#define DRAIN(CC)                                                                   \
        do {                                                                        \
            _Pragma("unroll")                                                       \
            for (int k = 0; k < 3; ++k) {                                           \
                int i  = k * 64 + lane;                                             \
                int p  = i / 12;                                                    \
                int q  = i - p * 12;                                                \
                int g2 = q / 3;                                                     \
                int jj = q - g2 * 3;                                                \
                int t  = (CC) * CHUNK + p - 3;                                      \
                float val = ring[(CC) & 1][p][g2 * 16 + 12 + jj];                   \
                if (t >= 0 && t < T_SEQ)                                            \
                    out[(size_t)t * 192 + (blk * 4 + g2) * 3 + jj] = val;           \
            }                                                                       \
        } while (0)

        FILL(0, 0);
        FILL(1, CHUNK);
        RING_BARRIER();

#pragma unroll 1
        for (int c = 0; c < NCHUNK; ++c) {
            const int f = c + 2;
            if (f <= 127) FILL(f % 3, f * CHUNK);
            if (c >= 1)   DRAIN(c - 1);
            RING_BARRIER();
        }
        DRAIN(NCHUNK - 1);
#undef FILL
#undef DRAIN
    }
}

// ---------------------------------------------------------------------------
extern "C" void kernel_launch(void* const* d_in, const int* in_sizes, int n_in,
                              void* d_out, int out_size, void* d_ws, size_t ws_size,
                              hipStream_t stream) {
    const float* x         = (const float*)d_in[0];
    const float* hxs       = (const float*)d_in[1];
    const float* w_ih0     = (const float*)d_in[2];
    const float* w_hh0     = (const float*)d_in[3];
    const float* b_ih0     = (const float*)d_in[4];
    const float* b_hh0     = (const float*)d_in[5];
    const float* w_ih_rest = (const float*)d_in[6];
    const float* w_hh_rest = (const float*)d_in[7];
    const float* b_ih_rest = (const float*)d_in[8];
    const float* b_hh_rest = (const float*)d_in[9];
    float* out = (float*)d_out;
    float* gx0 = (float*)d_ws;   // T*64*9*4 = 4.72 MB

    hipLaunchKernelGGL(gx0_kernel, dim3(2048), dim3(256), 0, stream,
                       x, w_ih0, b_ih0, gx0);
    hipLaunchKernelGGL(gru_scan, dim3(16), dim3(128), 0, stream,
                       gx0, hxs, w_hh0, b_hh0, w_ih_rest, w_hh_rest,
                       b_ih_rest, b_hh_rest, out);
}

// Round 6
// 223.338 us; speedup vs baseline: 2.3166x; 1.0393x over previous
//
#include <hip/hip_runtime.h>
#include <hip/hip_bf16.h>

#define T_SEQ 2048
#define CHUNK 16
#define NCHUNK 129           // 129 chunks x 16 steps = 2064 wave-steps >= 2051
#define L2E  1.44269504088896340736f
#define L2E2 2.88539008177792681472f

typedef float vf2 __attribute__((ext_vector_type(2)));

// ---------------- cross-lane / math helpers ----------------
template<int CTRL>
__device__ __forceinline__ float dppmov(float v) {
    return __int_as_float(__builtin_amdgcn_update_dpp(
        0, __float_as_int(v), CTRL, 0xF, 0xF, true));
}
template<int CTRL>
__device__ __forceinline__ float dppadd(float v) { return v + dppmov<CTRL>(v); }
__device__ __forceinline__ float swzadd16(float v) {
    return v + __int_as_float(__builtin_amdgcn_ds_swizzle(__float_as_int(v), 0x401F));
}
__device__ __forceinline__ float frcp(float x) { return __builtin_amdgcn_rcpf(x); }
__device__ __forceinline__ float ex2(float x)  { return __builtin_amdgcn_exp2f(x); }
__device__ __forceinline__ vf2 pkfma(vf2 a, float b, vf2 c) {
    vf2 bb = { b, b };
    return __builtin_elementwise_fma(a, bb, c);   // -> v_pk_fma_f32
}

#define RING_BARRIER() asm volatile("s_waitcnt lgkmcnt(0)\ns_barrier" ::: "memory")

// ---------------------------------------------------------------------------
// Kernel 1 (HBM roofline): gx0[row][g] = (dot+b)*scale
// scale = +log2e for r,z rows (g<6); -2*log2e for n rows (g>=6) so the scan
// computes er/ez = ex2(-a) and en = ex2(argn) with zero extra scaling ops.
// ---------------------------------------------------------------------------
__global__ __launch_bounds__(256) void gx0_kernel(
    const float* __restrict__ x, const float* __restrict__ w,
    const float* __restrict__ bias, float* __restrict__ gx0)
{
    const int lane = threadIdx.x & 63;
    const int gw   = (blockIdx.x * 256 + threadIdx.x) >> 6;

    float4 wA[9], wB[9];
#pragma unroll
    for (int g = 0; g < 9; ++g) {
        const float s = (g < 6) ? L2E : -L2E2;
        float4 a = *(const float4*)&w[g * 512 + lane * 4];
        float4 b = *(const float4*)&w[g * 512 + 256 + lane * 4];
        wA[g] = make_float4(a.x * s, a.y * s, a.z * s, a.w * s);
        wB[g] = make_float4(b.x * s, b.y * s, b.z * s, b.w * s);
    }
    const float bval = (lane < 9) ? bias[lane] * ((lane < 6) ? L2E : -L2E2) : 0.f;

    size_t row0 = (size_t)gw * 16;
    const float4* xp = (const float4*)(x + row0 * 512);
    float4 xa = xp[lane];
    float4 xb = xp[64 + lane];

#pragma unroll 1
    for (int i = 0; i < 16; ++i) {
        float4 na = xa, nb = xb;
        if (i < 15) {
            na = xp[(i + 1) * 128 + lane];
            nb = xp[(i + 1) * 128 + 64 + lane];
        }
        float r[9];
#pragma unroll
        for (int g = 0; g < 9; ++g) {
            float s = xa.x * wA[g].x;
            s = fmaf(xa.y, wA[g].y, s);
            s = fmaf(xa.z, wA[g].z, s);
            s = fmaf(xa.w, wA[g].w, s);
            s = fmaf(xb.x, wB[g].x, s);
            s = fmaf(xb.y, wB[g].y, s);
            s = fmaf(xb.z, wB[g].z, s);
            s = fmaf(xb.w, wB[g].w, s);
            s = dppadd<0xB1>(s);
            s = dppadd<0x4E>(s);
            s = dppadd<0x124>(s);
            s = dppadd<0x128>(s);
            s = swzadd16(s);
            s += __shfl_xor(s, 32, 64);
            r[g] = s;
        }
        float o = r[0];
#pragma unroll
        for (int g = 1; g < 9; ++g) o = (lane == g) ? r[g] : o;
        if (lane < 9) gx0[(row0 + i) * 9 + lane] = o + bval;
        xa = na; xb = nb;
    }
}

// ---------------------------------------------------------------------------
// Kernel 2: producer/consumer GRU scan, fused single-division gate math.
// With ez = e^-az, en = e^-2an, r = 1/(1+e^-ar):
//   h' = (en*(h-ez) + (h+ez)) / ((1+en)*(1+ez))
// Producer step: 1 ds_read_b128 + 6 DPP + 7 pk-ops + 6 fma + 4 trans +
// ~8 scalar VALU + 1 ds_write.
// ---------------------------------------------------------------------------
__global__ __launch_bounds__(128) void gru_scan(
    const float* __restrict__ gx0,        // [T*64*9] pre-scaled, incl. b_ih0
    const float* __restrict__ hxs,
    const float* __restrict__ w_hh0, const float* __restrict__ b_hh0,
    const float* __restrict__ w_ih_rest, const float* __restrict__ w_hh_rest,
    const float* __restrict__ b_ih_rest, const float* __restrict__ b_hh_rest,
    float* __restrict__ out)              // [T*64*3 + 4*64*3]
{
    __shared__ float4 gxb[3][CHUNK][64];   // 48 KB
    __shared__ float  ring[2][CHUNK][64];  // 8 KB
    const int tid  = threadIdx.x;
    const int lane = tid & 63;

    if (tid < 64) {
        // ============================ producer ============================
        const int grp = lane >> 4;
        const int r_  = lane & 15;
        const int l   = r_ >> 2;
        const int j   = r_ & 3;
        const bool jok = (j < 3);
        const bool is0 = (l == 0);
        const int  b   = blockIdx.x * 4 + grp;
        const int  row0 = jok ? j : 0;

        // packed r/z rows (scale +L2E, b_ih folded into bh) ; n row scale -L2E2
        vf2 wi01[3], wh01[3], bh01;
        float wi2[3], wh2[3], bh2;
        {
            float wi[3][3], wh[3][3], bh[3];
            const float sc[3] = {L2E, L2E, -L2E2};
#pragma unroll
            for (int m = 0; m < 3; ++m) {
                const int row = m * 3 + row0;
                if (l == 0) {
                    bh[m] = b_hh0[row] * sc[m];
#pragma unroll
                    for (int k = 0; k < 3; ++k) { wi[m][k] = 0.f; wh[m][k] = w_hh0[row * 3 + k] * sc[m]; }
                } else {
                    float bb = b_hh_rest[(l - 1) * 9 + row];
                    if (m < 2) bb += b_ih_rest[(l - 1) * 9 + row];
                    bh[m] = bb * sc[m];
#pragma unroll
                    for (int k = 0; k < 3; ++k) {
                        wi[m][k] = w_ih_rest[((l - 1) * 9 + row) * 3 + k] * sc[m];
                        wh[m][k] = w_hh_rest[((l - 1) * 9 + row) * 3 + k] * sc[m];
                    }
                }
            }
#pragma unroll
            for (int k = 0; k < 3; ++k) {
                wi01[k] = (vf2){wi[0][k], wi[1][k]};
                wh01[k] = (vf2){wh[0][k], wh[1][k]};
                wi2[k] = wi[2][k]; wh2[k] = wh[2][k];
            }
            bh01 = (vf2){bh[0], bh[1]};
            bh2  = bh[2];
        }
        const float bi2 = is0 ? 0.f : b_ih_rest[(l - 1) * 9 + 6 + row0] * (-L2E2);

        // constant gx slots for lanes the consumer never writes (l>0, or j==3)
        if (!(is0 && jok)) {
            const float4 cv = make_float4(0.f, 0.f, bi2, 0.f);
#pragma unroll
            for (int f = 0; f < 3; ++f)
                for (int st = 0; st < CHUNK; ++st)
                    gxb[f][st][lane] = cv;
        }
        float h = jok ? hxs[(l * 64 + b) * 3 + j] : 0.f;

        RING_BARRIER();   // consumer has prefilled bufs 0,1

        float4 gp[4];
#pragma unroll
        for (int k = 0; k < 4; ++k) gp[k] = gxb[0][k][lane];

        int bufc = 0;

#define GSTEP(P, MODE, TT)                                                          \
        do {                                                                        \
            float4 cc = gp[(P) & 3];                                                \
            if ((P) < CHUNK - 4) gp[(P) & 3] = gxb[bufc][(P) + 4][lane];            \
            else                 gp[(P) & 3] = gxb[bufn][(P) - (CHUNK - 4)][lane];  \
            float hv0 = dppmov<0x00>(h);                                            \
            float hv1 = dppmov<0x55>(h);                                            \
            float hv2 = dppmov<0xAA>(h);                                            \
            float xv0 = dppmov<0x114>(hv0);                                         \
            float xv1 = dppmov<0x114>(hv1);                                         \
            float xv2 = dppmov<0x114>(hv2);                                         \
            vf2 grz = (vf2){cc.x, cc.y};                                            \
            grz = pkfma(wi01[0], xv0, grz);                                         \
            grz = pkfma(wi01[1], xv1, grz);                                         \
            grz = pkfma(wi01[2], xv2, grz);                                         \
            vf2 ghrz = bh01;                                                        \
            ghrz = pkfma(wh01[0], hv0, ghrz);                                       \
            ghrz = pkfma(wh01[1], hv1, ghrz);                                       \
            ghrz = pkfma(wh01[2], hv2, ghrz);                                       \
            vf2 arz = grz + ghrz;                                                   \
            float gxn = fmaf(wi2[0], xv0, fmaf(wi2[1], xv1, fmaf(wi2[2], xv2, cc.z))); \
            float ghn = fmaf(wh2[0], hv0, fmaf(wh2[1], hv1, fmaf(wh2[2], hv2, bh2))); \
            float er = ex2(-arz.x);                                                 \
            float ez = ex2(-fmaxf(arz.y, -60.f));                                   \
            float rr = frcp(1.0f + er);                                             \
            float argn = fminf(fmaf(rr, ghn, gxn), 60.f);                           \
            float en = ex2(argn);                                                   \
            float N  = fmaf(en, h - ez, h + ez);                                    \
            float en1 = en + 1.0f;                                                  \
            float D  = fmaf(en1, ez, en1);                                          \
            float hn = N * frcp(D);                                                 \
            if (MODE == 0)      h = ((TT) >= 0)    ? hn : h;                        \
            else if (MODE == 2) h = ((TT) < T_SEQ) ? hn : h;                        \
            else                h = hn;                                             \
            ring[CB][(P)][lane] = hn;                                               \
        } while (0)

        // ---- chunk 0: steps 0..15, t>=0 guard on first 4 ----
        {
            const int bufn = 1; const int CB = 0;
#pragma unroll
            for (int p = 0; p < 4; ++p)  GSTEP(p, 0, p - l);
#pragma unroll
            for (int p = 4; p < 16; ++p) GSTEP(p, 1, 0);
            RING_BARRIER();
            bufc = 1;
        }
        // ---- chunks 1..127: no guards ----
#pragma unroll 1
        for (int c = 1; c < 128; ++c) {
            const int bufn = (bufc == 2) ? 0 : bufc + 1;
            const int CB = c & 1;
#pragma unroll
            for (int p = 0; p < 16; ++p) GSTEP(p, 1, 0);
            RING_BARRIER();
            bufc = bufn;
        }
        // ---- chunk 128 tail: s = 2048..2051, t<T guard ----
        {
            const int bufn = (bufc == 2) ? 0 : bufc + 1;
            const int CB = 0;   // 128 & 1 == 0
#pragma unroll
            for (int p = 0; p < 4; ++p) GSTEP(p, 2, 2048 + p - l);
            RING_BARRIER();
        }
#undef GSTEP
        // final hidden states (once, off critical path)
        if (jok) out[(size_t)T_SEQ * 192 + (l * 64 + b) * 3 + j] = h;
    } else {
        // ============================ consumer ============================
        const int blk = blockIdx.x;
        float* gxs = (float*)gxb;

#define FILL(F, T0)                                                                 \
        do {                                                                        \
            _Pragma("unroll")                                                       \
            for (int k = 0; k < 9; ++k) {                                           \
                int i  = k * 64 + lane;                                             \
                int st = i / 36;                                                    \
                int pos = i - st * 36;                                              \
                int bl = pos / 9;                                                   \
                int g  = pos - bl * 9;                                              \
                int m  = g / 3;                                                     \
                int jj = g - m * 3;                                                 \
                float val = gx0[(size_t)((T0) + st) * 576 + (blk * 4 + bl) * 9 + g];\
                gxs[(((F) * CHUNK + st) * 64 + bl * 16 + jj) * 4 + m] = val;        \
            }                                                                       \
        } while (0)

#define DRAIN(CC)                                                                   \
        do {                                                                        \
            _Pragma("unroll")                                                       \
            for (int k = 0; k < 3; ++k) {                                           \
                int i  = k * 64 + lane;                                             \
                int p  = i / 12;                                                    \
                int q  = i - p * 12;                                                \
                int g2 = q / 3;                                                     \
                int jj = q - g2 * 3;                                                \
                int t  = (CC) * CHUNK + p - 3;                                      \
                float val = ring[(CC) & 1][p][g2 * 16 + 12 + jj];                   \
                if (t >= 0 && t < T_SEQ)                                            \
                    out[(size_t)t * 192 + (blk * 4 + g2) * 3 + jj] = val;           \
            }                                                                       \
        } while (0)

        FILL(0, 0);
        FILL(1, CHUNK);
        RING_BARRIER();

#pragma unroll 1
        for (int c = 0; c < NCHUNK; ++c) {
            const int f = c + 2;
            if (f <= 127) FILL(f % 3, f * CHUNK);
            if (c >= 1)   DRAIN(c - 1);
            RING_BARRIER();
        }
        DRAIN(NCHUNK - 1);
#undef FILL
#undef DRAIN
    }
}

// ---------------------------------------------------------------------------
extern "C" void kernel_launch(void* const* d_in, const int* in_sizes, int n_in,
                              void* d_out, int out_size, void* d_ws, size_t ws_size,
                              hipStream_t stream) {
    const float* x         = (const float*)d_in[0];
    const float* hxs       = (const float*)d_in[1];
    const float* w_ih0     = (const float*)d_in[2];
    const float* w_hh0     = (const float*)d_in[3];
    const float* b_ih0     = (const float*)d_in[4];
    const float* b_hh0     = (const float*)d_in[5];
    const float* w_ih_rest = (const float*)d_in[6];
    const float* w_hh_rest = (const float*)d_in[7];
    const float* b_ih_rest = (const float*)d_in[8];
    const float* b_hh_rest = (const float*)d_in[9];
    float* out = (float*)d_out;
    float* gx0 = (float*)d_ws;   // T*64*9*4 = 4.72 MB

    hipLaunchKernelGGL(gx0_kernel, dim3(2048), dim3(256), 0, stream,
                       x, w_ih0, b_ih0, gx0);
    hipLaunchKernelGGL(gru_scan, dim3(16), dim3(128), 0, stream,
                       gx0, hxs, w_hh0, b_hh0, w_ih_rest, w_hh_rest,
                       b_ih_rest, b_hh_rest, out);
}